// Round 6
// baseline (29.940 us; speedup 1.0000x reference)
//
#include <hip/hip_runtime.h>
#include <hip/hip_bf16.h>

// KAN layer: out[n,i] = sum_{g,d} splines[i,g,d] * relu(1 - |x[n,d] - grid[g]|)
// B=8192, D=192, G=192, O=16.
//
// x,grid in [0,1] => relu is identity. Piecewise-linear in x per d:
//   sum_g s*(1-|x-r_g|) = Cp(g*) - x*A(g*),  g* = floor(x*191)
// A = 2P - T, Cp = T - U + 2Q; P,Q inclusive prefix sums of s and s*grid
// over g. Table tab[d][g][i] packed as u32 {lo=bf16(A), hi=bf16(Cp)}.
//
// R5 lesson: random L2 gather runs at only ~1/3 of streaming BW. So:
// stage 12-d table slices (144 KB) in LDS (streamed fill, 37 MB chip-wide),
// gather from LDS instead of L2; partial sums to ws, tiny reduce kernel.

#define Dn 192
#define Gn 192
#define On 16
#define Bn 8192

#define CHUNKS 16
#define CD (Dn / CHUNKS)        // 12 d's per chunk
#define NBLK 16
#define NPB (Bn / NBLK)         // 512 n's per block
#define TPB 1024
#define SLICE (CD * Gn * On)    // 36864 u32 = 144 KB

__device__ __forceinline__ unsigned short f2bf(float f) {
    union { float f; unsigned u; } v; v.f = f;
    unsigned r = v.u + 0x7FFF + ((v.u >> 16) & 1);   // RTN-even
    return (unsigned short)(r >> 16);
}

// ---------------- precompute: one wave per (d,i) -------------------------
__global__ __launch_bounds__(256) void kan_pre(const float* __restrict__ sp,
                                               const float* __restrict__ grid,
                                               unsigned* __restrict__ tab) {
    int gtid = blockIdx.x * blockDim.x + threadIdx.x;
    int w = gtid >> 6;          // global wave id
    int lane = threadIdx.x & 63;
    if (w >= Dn * On) return;   // 3072 waves
    int d = w >> 4;
    int i = w & 15;

    int g0 = lane * 3;  // 192 = 64 lanes * 3 g's each
    const float* s_base = sp + (size_t)i * Gn * Dn + d;   // splines[i,g,d]
    float s0 = s_base[(size_t)(g0 + 0) * Dn];
    float s1 = s_base[(size_t)(g0 + 1) * Dn];
    float s2 = s_base[(size_t)(g0 + 2) * Dn];
    float q0 = s0 * grid[g0 + 0];
    float q1 = s1 * grid[g0 + 1];
    float q2 = s2 * grid[g0 + 2];

    float lp1 = s0 + s1, lp2 = lp1 + s2;
    float lq1 = q0 + q1, lq2 = lq1 + q2;
    float sP = lp2, sQ = lq2;
    #pragma unroll
    for (int off = 1; off < 64; off <<= 1) {
        float pP = __shfl_up(sP, off);
        float pQ = __shfl_up(sQ, off);
        if (lane >= off) { sP += pP; sQ += pQ; }
    }
    float exP = sP - lp2, exQ = sQ - lq2;
    float T = __shfl(sP, 63);
    float U = __shfl(sQ, 63);

    float P[3] = { exP + s0, exP + lp1, exP + lp2 };
    float Q[3] = { exQ + q0, exQ + lq1, exQ + lq2 };

    #pragma unroll
    for (int k = 0; k < 3; ++k) {
        int g = g0 + k;
        float A  = 2.0f * P[k] - T;
        float Cp = T - U + 2.0f * Q[k];
        unsigned packed = (unsigned)f2bf(A) | ((unsigned)f2bf(Cp) << 16);
        tab[((size_t)d * Gn + g) * On + i] = packed;
    }
}

// ---------------- main: block = (n-group, d-chunk), table slice in LDS ---
__global__ __launch_bounds__(TPB) void kan_main_lds(const float* __restrict__ x,
                                                    const unsigned* __restrict__ tab,
                                                    float* __restrict__ partial) {
    __shared__ unsigned lds[SLICE];     // 144 KB -> 1 block/CU
    int t  = threadIdx.x;
    int nb = blockIdx.x;                // 0..15
    int c  = blockIdx.y;                // 0..15

    // streamed, coalesced fill of this chunk's table slice
    const uint4* src = (const uint4*)(tab + (size_t)c * SLICE);
    uint4* dst = (uint4*)lds;
    #pragma unroll
    for (int j = 0; j < SLICE / 4 / TPB; ++j)   // 9 uint4 per thread
        dst[t + j * TPB] = src[t + j * TPB];
    __syncthreads();

    int i    = t & 15;
    int nsub = t >> 4;                  // 0..63
    int d0   = c * CD;
    float* pout = partial + (size_t)c * Bn * On;

    #pragma unroll
    for (int k = 0; k < NPB / 64; ++k) {        // 8 n's per thread
        int n = nb * NPB + nsub + 64 * k;
        const float4* xr = (const float4*)(x + (size_t)n * Dn + d0);  // 3 float4
        float acc = 0.0f;
        #pragma unroll
        for (int d4 = 0; d4 < CD / 4; ++d4) {
            float4 xv = xr[d4];
            float vx[4] = { xv.x, xv.y, xv.z, xv.w };
            #pragma unroll
            for (int kk = 0; kk < 4; ++kk) {
                float v = vx[kk];
                int g = (int)(v * 191.0f);
                g = (g < 0) ? 0 : (g > 191 ? 191 : g);
                unsigned e = lds[((d4 * 4 + kk) * Gn + g) * On + i];
                union { unsigned u; float f; } A, C;
                A.u = e << 16;            // bf16 lo -> f32
                C.u = e & 0xFFFF0000u;    // bf16 hi -> f32
                acc += C.f;
                acc = fmaf(-v, A.f, acc); // acc += Cp - x*A
            }
        }
        pout[(size_t)n * On + i] = acc;   // coalesced
    }
}

// ---------------- reduce: out = sum_c partial[c] --------------------------
__global__ __launch_bounds__(256) void kan_reduce(const float* __restrict__ partial,
                                                  float* __restrict__ out) {
    int j = blockIdx.x * 256 + threadIdx.x;     // 131072 threads
    float s = 0.0f;
    #pragma unroll
    for (int c = 0; c < CHUNKS; ++c)
        s += partial[(size_t)c * Bn * On + j];  // coalesced per c
    out[j] = s;
}

// ---------------- fallback (ws too small): direct computation ------------
__global__ __launch_bounds__(256) void kan_naive(const float* __restrict__ x,
                                                 const float* __restrict__ sp,
                                                 const float* __restrict__ grid,
                                                 float* __restrict__ out) {
    __shared__ float xs[Dn];
    __shared__ float gsh[Gn];
    __shared__ float red[4];
    int n = blockIdx.x;
    int t = threadIdx.x;
    if (t < Dn) { xs[t] = x[(size_t)n * Dn + t]; gsh[t] = grid[t]; }
    __syncthreads();
    float acc[On];
    #pragma unroll
    for (int i = 0; i < On; ++i) acc[i] = 0.0f;
    for (int idx = t; idx < Gn * Dn; idx += 256) {
        int g = idx / Dn;
        int d = idx - g * Dn;
        float b = fmaxf(0.0f, 1.0f - fabsf(xs[d] - gsh[g]));
        #pragma unroll
        for (int i = 0; i < On; ++i)
            acc[i] += sp[(size_t)i * Gn * Dn + idx] * b;
    }
    for (int i = 0; i < On; ++i) {
        float v = acc[i];
        #pragma unroll
        for (int off = 32; off > 0; off >>= 1) v += __shfl_down(v, off);
        if ((t & 63) == 0) red[t >> 6] = v;
        __syncthreads();
        if (t == 0) out[(size_t)n * On + i] = red[0] + red[1] + red[2] + red[3];
        __syncthreads();
    }
}

extern "C" void kernel_launch(void* const* d_in, const int* in_sizes, int n_in,
                              void* d_out, int out_size, void* d_ws, size_t ws_size,
                              hipStream_t stream) {
    const float* x    = (const float*)d_in[0];
    const float* sp   = (const float*)d_in[1];
    const float* grid = (const float*)d_in[2];
    float* out = (float*)d_out;

    const size_t TAB_BYTES  = (size_t)Dn * Gn * On * sizeof(unsigned);        // 2.36 MB
    const size_t PART_BYTES = (size_t)CHUNKS * Bn * On * sizeof(float);       // 8.39 MB
    if (ws_size >= TAB_BYTES + PART_BYTES) {
        unsigned* tab   = (unsigned*)d_ws;
        float* partial  = (float*)((char*)d_ws + TAB_BYTES);
        kan_pre<<<(Dn * On * 64 + 255) / 256, 256, 0, stream>>>(sp, grid, tab);
        kan_main_lds<<<dim3(NBLK, CHUNKS), TPB, 0, stream>>>(x, tab, partial);
        kan_reduce<<<Bn * On / 256, 256, 0, stream>>>(partial, out);
    } else {
        kan_naive<<<Bn, 256, 0, stream>>>(x, sp, grid, out);
    }
}